// Round 12
// baseline (289.253 us; speedup 1.0000x reference)
//
#include <hip/hip_runtime.h>

#define BB 8
#define TT 1024
#define DD 512
#define DD2 1024
#define HH 8
#define HDIM 64
#define TP (TT + 2)

typedef short short8 __attribute__((ext_vector_type(8)));
typedef float floatx4 __attribute__((ext_vector_type(4)));

typedef const __attribute__((address_space(1))) unsigned int* gas_ptr;
typedef __attribute__((address_space(3))) unsigned int* las_ptr;

__device__ __forceinline__ unsigned short f2bf(float f) {
    union { float f; unsigned u; } v; v.f = f;
    unsigned r = v.u + 0x7fffu + ((v.u >> 16) & 1u);
    return (unsigned short)(r >> 16);
}

// async global->LDS, 16B per lane, LDS dst = wave-uniform base + lane*16
__device__ __forceinline__ void gl2lds16(const void* g, void* l) {
    __builtin_amdgcn_global_load_lds((gas_ptr)g, (las_ptr)l, 16, 0, 0);
}

// ---------------- fused prep kernel ----------------
#define NXBLK 16416
#define NW1BLK 9216
#define NW2BLK 6144
#define NZBLK 1024
__global__ void k_prep(const float* __restrict__ x, const float* __restrict__ w0,
                       const float* __restrict__ w1, const float* __restrict__ w2,
                       const float* __restrict__ wo,
                       unsigned short* __restrict__ xp, unsigned short* __restrict__ wqkv,
                       unsigned short* __restrict__ w2k, unsigned short* __restrict__ vp,
                       float* __restrict__ gbuf) {
    int blk = blockIdx.x;
    if (blk < NXBLK) {
        int idx = blk * 256 + threadIdx.x;
        int c = idx % DD;
        int rt = idx / DD;
        int row = rt % TP;
        int b = rt / TP;
        float v = 0.f;
        if (row >= 1 && row <= TT) v = x[(b * TT + row - 1) * DD + c];
        xp[idx] = f2bf(v);
        return;
    }
    blk -= NXBLK;
    if (blk < NW1BLK) {
        // W(qkv) B-frag-major: [proj][k][ci0(16)][co0(32)][lane(64)][e(8)]
        int idx = blk * 256 + threadIdx.x;
        int e = idx & 7;
        int lane = (idx >> 3) & 63;
        int co0 = (idx >> 9) & 31;
        int ci0 = (idx >> 14) & 15;
        int rest = idx >> 18;
        int k = rest % 3, p = rest / 3;
        int co = co0 * 16 + (lane & 15);
        int ci = ci0 * 32 + (lane >> 4) * 8 + e;
        const float* w = (p == 0) ? w0 : ((p == 1) ? w1 : w2);
        wqkv[idx] = f2bf(w[(co * DD + ci) * 3 + k]);
        return;
    }
    blk -= NW1BLK;
    if (blk < NW2BLK) {
        // W2 B-frag-major: [k][ci0(32)][co0(32)][lane(64)][e(8)]
        int idx = blk * 256 + threadIdx.x;
        int e = idx & 7;
        int lane = (idx >> 3) & 63;
        int co0 = (idx >> 9) & 31;
        int ci0 = (idx >> 14) & 31;
        int k = idx >> 19;
        int co = co0 * 16 + (lane & 15);
        int ci = ci0 * 32 + (lane >> 4) * 8 + e;
        w2k[idx] = f2bf(wo[(co * DD2 + ci) * 3 + k]);
        return;
    }
    blk -= NW2BLK;
    {
        int idx = blk * 256 + threadIdx.x;
        if (idx < BB * 2 * 2 * DD) {
            int c = idx % (2 * DD);
            int t1 = idx / (2 * DD);
            int row = (t1 & 1) ? (TT + 1) : 0;
            int b = t1 >> 1;
            vp[(b * TP + row) * (2 * DD) + c] = 0;
        }
        if (idx < 64 * HDIM * HDIM) gbuf[idx] = 0.f;
    }
}

// ---------------- QKV conv: 64x128 tile, BK=32 dbuf, 2x2 wave split, W streamed -------
// grid (T/64=16, 512/128=4, B*3=24) = 1536 blocks. Wave (wm,wn): rows wm*32..+32,
// co wn*64..+64 -> A-frag ds_reads 6/it/wave (halved LDS-pipe pressure vs pure-N split).
__global__ __launch_bounds__(256) void k_qkv_conv(
    const unsigned short* __restrict__ xp, const unsigned short* __restrict__ wfrag,
    const float* __restrict__ b11, const float* __restrict__ b12, const float* __restrict__ b13,
    unsigned short* __restrict__ q, unsigned short* __restrict__ qt,
    unsigned short* __restrict__ kfrag, unsigned short* __restrict__ kt,
    unsigned short* __restrict__ v, unsigned short* __restrict__ vtfrag) {
    __shared__ short As[2][80 * 32];
    int wave = threadIdx.x >> 6, lane = threadIdx.x & 63;
    int l15 = lane & 15, quad = lane >> 4;
    int wm = wave >> 1, wn = wave & 1;
    int tb = blockIdx.x * 64;
    int cb = blockIdx.y * 128;
    int proj = blockIdx.z % 3, b = blockIdx.z / 3;
    const short* A = (const short*)xp + b * TP * DD;
    const short* WF = (const short*)wfrag + (size_t)proj * 786432 + lane * 8;
    int srow = lane >> 2;
    int scs = (((lane & 3) ^ ((lane >> 3) & 3)) << 3);
    int co0b = (cb >> 4) + wn * 4;

    floatx4 acc[2][4];
#pragma unroll
    for (int mi = 0; mi < 2; ++mi)
#pragma unroll
        for (int ni = 0; ni < 4; ++ni) acc[mi][ni] = (floatx4){0.f, 0.f, 0.f, 0.f};

    auto stage = [&](int it) {
        short* dst = As[it & 1];
        int cib = it * 32;
        for (int j = wave; j < 5; j += 4)
            gl2lds16(A + (tb + j * 16 + srow) * DD + cib + scs, &dst[j * 512]);
    };

    stage(0);
    __syncthreads();

    for (int it = 0; it < 16; ++it) {
        if (it < 15) stage(it + 1);
        const short* Asb = As[it & 1];
        short8 bf[3][4];
#pragma unroll
        for (int k = 0; k < 3; ++k)
#pragma unroll
            for (int ni = 0; ni < 4; ++ni)
                bf[k][ni] = *(const short8*)(WF + ((size_t)((k * 16 + it) * 32 + co0b + ni) << 9));
#pragma unroll
        for (int k = 0; k < 3; ++k) {
            short8 af[2];
#pragma unroll
            for (int mi = 0; mi < 2; ++mi) {
                int arow = wm * 32 + mi * 16 + l15 + k;
                af[mi] = *(const short8*)&Asb[arow * 32 + ((quad ^ ((arow >> 1) & 3)) << 3)];
            }
#pragma unroll
            for (int mi = 0; mi < 2; ++mi)
#pragma unroll
                for (int ni = 0; ni < 4; ++ni)
                    acc[mi][ni] = __builtin_amdgcn_mfma_f32_16x16x32_bf16(af[mi], bf[k][ni], acc[mi][ni], 0, 0, 0);
        }
        __syncthreads();
    }

    const float* bias = (proj == 0) ? b11 : ((proj == 1) ? b12 : b13);
#pragma unroll
    for (int ni = 0; ni < 4; ++ni) {
        int co = cb + wn * 64 + ni * 16 + l15;
        float bv = bias[co];
        int h = co >> 6, hd = co & 63;
        int bh = b * HH + h;
#pragma unroll
        for (int mi = 0; mi < 2; ++mi) {
            int tbase = tb + wm * 32 + mi * 16 + quad * 4;
            unsigned short bb[4];
            ushort4 pk;
#pragma unroll
            for (int r = 0; r < 4; ++r) {
                float val = fmaxf(acc[mi][ni][r] + bv, 0.f);
                bb[r] = f2bf(val);
                ((unsigned short*)&pk)[r] = bb[r];
            }
            if (proj == 0) {
#pragma unroll
                for (int r = 0; r < 4; ++r)
                    q[((size_t)bh * TT + tbase + r) * HDIM + hd] = bb[r];
                *(ushort4*)&qt[((size_t)bh * HDIM + hd) * TT + tbase] = pk;
            } else if (proj == 1) {
                *(ushort4*)&kt[((size_t)bh * HDIM + hd) * TT + tbase] = pk;
                // K-frag layout: [bh][sblk][jr][kf][quad_a*16+l15a][8]; mi' = wm*2+mi
                int sblk = tbase >> 6;
                int jr = (quad & 1) + 2 * wm;
                int l15a_base = 4 * (quad >> 1) + 8 * mi;  // + r
                int kf = hd >> 5, quad_a = (hd >> 3) & 3, elem = hd & 7;
                size_t base = ((((size_t)bh * 16 + sblk) * 4 + jr) * 2 + kf) * 512 +
                              quad_a * 128 + elem;
#pragma unroll
                for (int r = 0; r < 4; ++r)
                    kfrag[base + (l15a_base + r) * 8] = bb[r];
            } else {
#pragma unroll
                for (int r = 0; r < 4; ++r)
                    v[((size_t)bh * TT + tbase + r) * HDIM + hd] = bb[r];
                // Vt-frag layout: [bh][sblk][df][kf][quad_a*16+l15a][8]; mi' = wm*2+mi
                int sblk = tbase >> 6;
                int df = hd >> 4, l15a = hd & 15;
                int kf = wm;
                int quad_a = 2 * mi + (quad >> 1);
                int elem = (quad & 1) * 4;
                size_t base = ((((size_t)bh * 16 + sblk) * 4 + df) * 2 + kf) * 512 +
                              (quad_a * 16 + l15a) * 8 + elem;
                *(ushort4*)&vtfrag[base] = pk;
            }
        }
    }
}

// ---------------- fused: time attention (x<16) + chan Gram partials (x>=16) ----------
// grid (20, B*H=64), block 256.
__global__ __launch_bounds__(256) void k_attn_gram(
    const unsigned short* __restrict__ q, const unsigned short* __restrict__ kfrag,
    const unsigned short* __restrict__ vtfrag, const unsigned short* __restrict__ qt,
    const unsigned short* __restrict__ kt, float* __restrict__ gbuf,
    unsigned short* __restrict__ vp) {
    int wave = threadIdx.x >> 6, lane = threadIdx.x & 63;
    int l15 = lane & 15, quad = lane >> 4;
    int bh = blockIdx.y;

    if (blockIdx.x < 16) {
        // ---- time attention: all-register flash, lane-linear frag loads ----
        int b = bh >> 3, h = bh & 7;
        int qr = blockIdx.x * 64 + wave * 16;
        const short* Q = (const short*)q + (size_t)bh * TT * HDIM;
        const short* KF = (const short*)kfrag + (size_t)bh * 16 * 8 * 512 + lane * 8;
        const short* VF = (const short*)vtfrag + (size_t)bh * 16 * 8 * 512 + lane * 8;

        short8 bq[2];
#pragma unroll
        for (int kf = 0; kf < 2; ++kf)
            bq[kf] = *(const short8*)(Q + (qr + l15) * HDIM + kf * 32 + quad * 8);

        floatx4 o[4];  // O^T accum: d = df*16 + quad*4 + r, q = l15
#pragma unroll
        for (int df = 0; df < 4; ++df) o[df] = (floatx4){0.f, 0.f, 0.f, 0.f};
        float lacc = 0.f;

        for (int sblk = 0; sblk < 16; ++sblk) {
            const short* kp = KF + sblk * 8 * 512;
            const short* vv = VF + sblk * 8 * 512;
            floatx4 c[4];
#pragma unroll
            for (int jr = 0; jr < 4; ++jr) c[jr] = (floatx4){0.f, 0.f, 0.f, 0.f};
#pragma unroll
            for (int jr = 0; jr < 4; ++jr) {
#pragma unroll
                for (int kf = 0; kf < 2; ++kf) {
                    short8 ak = *(const short8*)(kp + (jr * 2 + kf) * 512);
                    c[jr] = __builtin_amdgcn_mfma_f32_16x16x32_bf16(ak, bq[kf], c[jr], 0, 0, 0);
                }
            }
            short8 pb[2];
#pragma unroll
            for (int kf = 0; kf < 2; ++kf) {
                union { short8 s; unsigned u[4]; } pk;
#pragma unroll
                for (int half = 0; half < 2; ++half) {
                    floatx4 cc = c[2 * kf + half];
                    float p0 = __expf(cc[0] * 0.125f);
                    float p1 = __expf(cc[1] * 0.125f);
                    float p2 = __expf(cc[2] * 0.125f);
                    float p3 = __expf(cc[3] * 0.125f);
                    lacc += (p0 + p1) + (p2 + p3);
                    pk.u[half * 2] =
                        __builtin_amdgcn_perm(__float_as_uint(p1), __float_as_uint(p0), 0x07060302u);
                    pk.u[half * 2 + 1] =
                        __builtin_amdgcn_perm(__float_as_uint(p3), __float_as_uint(p2), 0x07060302u);
                }
                pb[kf] = pk.s;
            }
#pragma unroll
            for (int df = 0; df < 4; ++df) {
#pragma unroll
                for (int kf = 0; kf < 2; ++kf) {
                    short8 av = *(const short8*)(vv + (df * 2 + kf) * 512);
                    o[df] = __builtin_amdgcn_mfma_f32_16x16x32_bf16(av, pb[kf], o[df], 0, 0, 0);
                }
            }
        }

        lacc += __shfl_xor(lacc, 16);
        lacc += __shfl_xor(lacc, 32);
        float linv = 1.f / lacc;

        unsigned short* vrow = vp + (size_t)(b * TP + 1 + qr + l15) * (2 * DD) + h * 64;
#pragma unroll
        for (int df = 0; df < 4; ++df) {
            ushort4 pk;
#pragma unroll
            for (int r = 0; r < 4; ++r) ((unsigned short*)&pk)[r] = f2bf(o[df][r] * linv);
            *(ushort4*)&vrow[df * 16 + quad * 4] = pk;
        }
    } else {
        // ---- chan Gram partials (4-way T split) ----
        int tc = blockIdx.x - 16;
        const short* Qt = (const short*)qt + (size_t)bh * HDIM * TT;
        const short* Kt = (const short*)kt + (size_t)bh * HDIM * TT;

        floatx4 g[4];
#pragma unroll
        for (int nt = 0; nt < 4; ++nt) g[nt] = (floatx4){0.f, 0.f, 0.f, 0.f};

        int t0b = tc * 256;
        for (int t0 = 0; t0 < 256; t0 += 32) {
            short8 aq = *(const short8*)(Qt + (wave * 16 + l15) * TT + t0b + t0 + quad * 8);
#pragma unroll
            for (int nt = 0; nt < 4; ++nt) {
                short8 bk = *(const short8*)(Kt + (nt * 16 + l15) * TT + t0b + t0 + quad * 8);
                g[nt] = __builtin_amdgcn_mfma_f32_16x16x32_bf16(aq, bk, g[nt], 0, 0, 0);
            }
        }
        float* gb = gbuf + bh * HDIM * HDIM;
#pragma unroll
        for (int nt = 0; nt < 4; ++nt) {
#pragma unroll
            for (int r = 0; r < 4; ++r) {
                int row = wave * 16 + quad * 4 + r;
                atomicAdd(&gb[row * HDIM + nt * 16 + l15], g[nt][r]);
            }
        }
    }
}

// ---------------- channel attention: softmax + A.V (4-way T split) ----------------
__global__ __launch_bounds__(256) void k_chan_av(
    const float* __restrict__ gbuf, const unsigned short* __restrict__ v,
    unsigned short* __restrict__ vp) {
    __shared__ short lds_a[64 * 64];
    int wave = threadIdx.x >> 6, lane = threadIdx.x & 63;
    int l15 = lane & 15, quad = lane >> 4;
    int tc = blockIdx.x, bh = blockIdx.y;
    int b = bh >> 3, h = bh & 7;
    const float sc = 0.03125f;  // 1/sqrt(1024)

    if (threadIdx.x < 64) {
        const float* gb = gbuf + bh * HDIM * HDIM + threadIdx.x * HDIM;
        float mx = -3.0e38f;
        for (int j = 0; j < 64; ++j) mx = fmaxf(mx, gb[j] * sc);
        float sum = 0.f;
        for (int j = 0; j < 64; ++j) sum += __expf(gb[j] * sc - mx);
        float inv = 1.f / sum;
        for (int j = 0; j < 64; ++j)
            lds_a[threadIdx.x * 64 + j] = (short)f2bf(__expf(gb[j] * sc - mx) * inv);
    }
    __syncthreads();

    const short* V = (const short*)v + (size_t)bh * TT * HDIM;
    short8 pa[2];
#pragma unroll
    for (int kf = 0; kf < 2; ++kf)
        pa[kf] = *(const short8*)&lds_a[(wave * 16 + l15) * 64 + kf * 32 + quad * 8];

    for (int tt = 0; tt < 16; ++tt) {
        int ttile = tc * 16 + tt;
        floatx4 c = (floatx4){0.f, 0.f, 0.f, 0.f};
#pragma unroll
        for (int kf = 0; kf < 2; ++kf) {
            short8 bv = *(const short8*)(V + (ttile * 16 + l15) * HDIM + kf * 32 + quad * 8);
            c = __builtin_amdgcn_mfma_f32_16x16x32_bf16(pa[kf], bv, c, 0, 0, 0);
        }
        int t = ttile * 16 + l15;
#pragma unroll
        for (int r = 0; r < 4; ++r) {
            int crow = wave * 16 + quad * 4 + r;
            int tout = crow * 16 + (t >> 6);
            int col = 512 + ((t & 63) << 3) + h;
            vp[(b * TP + 1 + tout) * (2 * DD) + col] = f2bf(c[r]);
        }
    }
}

// ---------------- output conv: 64x128 tile, BK=32 dbuf, 2x2 wave split, W2 streamed ---
// grid (T/64=16, 512/128=4, B=8) = 512 blocks. Wave (wm,wn): rows wm*32..+32, co wn*64..+64.
__global__ __launch_bounds__(256) void k_out_conv(
    const unsigned short* __restrict__ vp, const unsigned short* __restrict__ w2k,
    const float* __restrict__ b2, float* __restrict__ out) {
    __shared__ short As[2][80 * 32];
    int wave = threadIdx.x >> 6, lane = threadIdx.x & 63;
    int l15 = lane & 15, quad = lane >> 4;
    int wm = wave >> 1, wn = wave & 1;
    int tb = blockIdx.x * 64;
    int cb = blockIdx.y * 128;
    int b = blockIdx.z;
    const short* A = (const short*)vp + b * TP * DD2;
    const short* WF = (const short*)w2k + lane * 8;
    int srow = lane >> 2;
    int scs = (((lane & 3) ^ ((lane >> 3) & 3)) << 3);
    int co0b = (cb >> 4) + wn * 4;

    floatx4 acc[2][4];
#pragma unroll
    for (int mi = 0; mi < 2; ++mi)
#pragma unroll
        for (int ni = 0; ni < 4; ++ni) acc[mi][ni] = (floatx4){0.f, 0.f, 0.f, 0.f};

    auto stage = [&](int it) {
        short* dst = As[it & 1];
        int cib = it * 32;
        for (int j = wave; j < 5; j += 4)
            gl2lds16(A + (tb + j * 16 + srow) * DD2 + cib + scs, &dst[j * 512]);
    };

    stage(0);
    __syncthreads();

    for (int it = 0; it < 32; ++it) {
        if (it < 31) stage(it + 1);
        const short* Asb = As[it & 1];
        short8 bf[3][4];
#pragma unroll
        for (int k = 0; k < 3; ++k)
#pragma unroll
            for (int ni = 0; ni < 4; ++ni)
                bf[k][ni] = *(const short8*)(WF + ((size_t)((k * 32 + it) * 32 + co0b + ni) << 9));
#pragma unroll
        for (int k = 0; k < 3; ++k) {
            short8 af[2];
#pragma unroll
            for (int mi = 0; mi < 2; ++mi) {
                int arow = wm * 32 + mi * 16 + l15 + k;
                af[mi] = *(const short8*)&Asb[arow * 32 + ((quad ^ ((arow >> 1) & 3)) << 3)];
            }
#pragma unroll
            for (int mi = 0; mi < 2; ++mi)
#pragma unroll
                for (int ni = 0; ni < 4; ++ni)
                    acc[mi][ni] = __builtin_amdgcn_mfma_f32_16x16x32_bf16(af[mi], bf[k][ni], acc[mi][ni], 0, 0, 0);
        }
        __syncthreads();
    }

#pragma unroll
    for (int ni = 0; ni < 4; ++ni) {
        int co = cb + wn * 64 + ni * 16 + l15;
        float bv = b2[co];
#pragma unroll
        for (int mi = 0; mi < 2; ++mi) {
#pragma unroll
            for (int r = 0; r < 4; ++r) {
                int t = tb + wm * 32 + mi * 16 + quad * 4 + r;
                out[((size_t)b * TT + t) * DD + co] = fmaxf(acc[mi][ni][r] + bv, 0.f);
            }
        }
    }
}

extern "C" void kernel_launch(void* const* d_in, const int* in_sizes, int n_in,
                              void* d_out, int out_size, void* d_ws, size_t ws_size,
                              hipStream_t stream) {
    const float* x = (const float*)d_in[0];
    const float* w11 = (const float*)d_in[1];
    const float* b11 = (const float*)d_in[2];
    const float* w12 = (const float*)d_in[3];
    const float* b12 = (const float*)d_in[4];
    const float* w13 = (const float*)d_in[5];
    const float* b13 = (const float*)d_in[6];
    const float* w2 = (const float*)d_in[7];
    const float* b2 = (const float*)d_in[8];
    float* out = (float*)d_out;

    char* ws = (char*)d_ws;
    size_t off = 0;
    auto alloc = [&](size_t bytes) {
        void* p = ws + off;
        off += (bytes + 255) & ~(size_t)255;
        return p;
    };
    unsigned short* xp = (unsigned short*)alloc((size_t)BB * TP * DD * 2);
    unsigned short* wqkv = (unsigned short*)alloc((size_t)9 * DD * DD * 2);
    unsigned short* w2k = (unsigned short*)alloc((size_t)3 * DD * DD2 * 2);
    unsigned short* q = (unsigned short*)alloc((size_t)BB * HH * TT * HDIM * 2);
    unsigned short* qt = (unsigned short*)alloc((size_t)BB * HH * TT * HDIM * 2);
    unsigned short* kfrag = (unsigned short*)alloc((size_t)BB * HH * TT * HDIM * 2);
    unsigned short* kt = (unsigned short*)alloc((size_t)BB * HH * TT * HDIM * 2);
    unsigned short* v = (unsigned short*)alloc((size_t)BB * HH * TT * HDIM * 2);
    unsigned short* vtfrag = (unsigned short*)alloc((size_t)BB * HH * TT * HDIM * 2);
    float* gbuf = (float*)alloc((size_t)64 * HDIM * HDIM * 4);
    unsigned short* vp = (unsigned short*)alloc((size_t)BB * TP * 2 * DD * 2);
    (void)alloc(65536);  // guard: halo staging reads up to 14 rows past buffer ends

    k_prep<<<NXBLK + NW1BLK + NW2BLK + NZBLK, 256, 0, stream>>>(x, w11, w12, w13, w2,
                                                                xp, wqkv, w2k, vp, gbuf);
    k_qkv_conv<<<dim3(TT / 64, DD / 128, BB * 3), 256, 0, stream>>>(xp, wqkv, b11, b12, b13,
                                                                    q, qt, kfrag, kt, v, vtfrag);
    k_attn_gram<<<dim3(20, BB * HH), 256, 0, stream>>>(q, kfrag, vtfrag, qt, kt, gbuf, vp);
    k_chan_av<<<dim3(4, BB * HH), 256, 0, stream>>>(gbuf, v, vp);
    k_out_conv<<<dim3(TT / 64, DD / 128, BB), 256, 0, stream>>>(vp, w2k, b2, out);
}

// Round 13
// 242.763 us; speedup vs baseline: 1.1915x; 1.1915x over previous
//
#include <hip/hip_runtime.h>

#define BB 8
#define TT 1024
#define DD 512
#define DD2 1024
#define HH 8
#define HDIM 64
#define TP (TT + 2)

typedef short short8 __attribute__((ext_vector_type(8)));
typedef float floatx4 __attribute__((ext_vector_type(4)));

typedef const __attribute__((address_space(1))) unsigned int* gas_ptr;
typedef __attribute__((address_space(3))) unsigned int* las_ptr;

__device__ __forceinline__ unsigned short f2bf(float f) {
    union { float f; unsigned u; } v; v.f = f;
    unsigned r = v.u + 0x7fffu + ((v.u >> 16) & 1u);
    return (unsigned short)(r >> 16);
}

// async global->LDS, 16B per lane, LDS dst = wave-uniform base + lane*16
__device__ __forceinline__ void gl2lds16(const void* g, void* l) {
    __builtin_amdgcn_global_load_lds((gas_ptr)g, (las_ptr)l, 16, 0, 0);
}

// ---------------- fused prep kernel ----------------
#define NXBLK 16416
#define NW1BLK 9216
#define NW2BLK 6144
#define NZBLK 1024
__global__ void k_prep(const float* __restrict__ x, const float* __restrict__ w0,
                       const float* __restrict__ w1, const float* __restrict__ w2,
                       const float* __restrict__ wo,
                       unsigned short* __restrict__ xp, unsigned short* __restrict__ wqkv,
                       unsigned short* __restrict__ w2k, unsigned short* __restrict__ vp,
                       float* __restrict__ gbuf) {
    int blk = blockIdx.x;
    if (blk < NXBLK) {
        int idx = blk * 256 + threadIdx.x;
        int c = idx % DD;
        int rt = idx / DD;
        int row = rt % TP;
        int b = rt / TP;
        float v = 0.f;
        if (row >= 1 && row <= TT) v = x[(b * TT + row - 1) * DD + c];
        xp[idx] = f2bf(v);
        return;
    }
    blk -= NXBLK;
    if (blk < NW1BLK) {
        // W(qkv) B-frag-major: [proj][k][ci0(16)][co0(32)][lane(64)][e(8)]
        int idx = blk * 256 + threadIdx.x;
        int e = idx & 7;
        int lane = (idx >> 3) & 63;
        int co0 = (idx >> 9) & 31;
        int ci0 = (idx >> 14) & 15;
        int rest = idx >> 18;
        int k = rest % 3, p = rest / 3;
        int co = co0 * 16 + (lane & 15);
        int ci = ci0 * 32 + (lane >> 4) * 8 + e;
        const float* w = (p == 0) ? w0 : ((p == 1) ? w1 : w2);
        wqkv[idx] = f2bf(w[(co * DD + ci) * 3 + k]);
        return;
    }
    blk -= NW1BLK;
    if (blk < NW2BLK) {
        // W2 B-frag-major: [k][ci0(32)][co0(32)][lane(64)][e(8)]
        int idx = blk * 256 + threadIdx.x;
        int e = idx & 7;
        int lane = (idx >> 3) & 63;
        int co0 = (idx >> 9) & 31;
        int ci0 = (idx >> 14) & 31;
        int k = idx >> 19;
        int co = co0 * 16 + (lane & 15);
        int ci = ci0 * 32 + (lane >> 4) * 8 + e;
        w2k[idx] = f2bf(wo[(co * DD2 + ci) * 3 + k]);
        return;
    }
    blk -= NW2BLK;
    {
        int idx = blk * 256 + threadIdx.x;
        if (idx < BB * 2 * 2 * DD) {
            int c = idx % (2 * DD);
            int t1 = idx / (2 * DD);
            int row = (t1 & 1) ? (TT + 1) : 0;
            int b = t1 >> 1;
            vp[(b * TP + row) * (2 * DD) + c] = 0;
        }
        if (idx < 64 * HDIM * HDIM) gbuf[idx] = 0.f;
    }
}

// ---------------- QKV conv: 128x128 tile, pure-N wave split, BK=32 dbuf, W streamed ---
// grid (T/128=8, 512/128=4, B*3=24) = 768 blocks. Wave w owns co [cb+w*32,+32); wave
// tile 128x32. Pure-N = zero W-frag duplication across waves (R12 lesson: W L2 traffic
// is the cost driver; ds_reads are cheap). Swizzle verified conflict-free (R10/R11).
__global__ __launch_bounds__(256) void k_qkv_conv(
    const unsigned short* __restrict__ xp, const unsigned short* __restrict__ wfrag,
    const float* __restrict__ b11, const float* __restrict__ b12, const float* __restrict__ b13,
    unsigned short* __restrict__ q, unsigned short* __restrict__ qt,
    unsigned short* __restrict__ kfrag, unsigned short* __restrict__ kt,
    unsigned short* __restrict__ v, unsigned short* __restrict__ vtfrag) {
    __shared__ short As[2][144 * 32];
    int wave = threadIdx.x >> 6, lane = threadIdx.x & 63;
    int l15 = lane & 15, quad = lane >> 4;
    int tb = blockIdx.x * 128;
    int cb = blockIdx.y * 128;
    int proj = blockIdx.z % 3, b = blockIdx.z / 3;
    const short* A = (const short*)xp + b * TP * DD;
    const short* WF = (const short*)wfrag + (size_t)proj * 786432 + lane * 8;
    int srow = lane >> 2;
    int scs = (((lane & 3) ^ ((lane >> 3) & 3)) << 3);
    int co0b = (cb >> 4) + wave * 2;

    floatx4 acc[8][2];
#pragma unroll
    for (int mi = 0; mi < 8; ++mi)
#pragma unroll
        for (int ni = 0; ni < 2; ++ni) acc[mi][ni] = (floatx4){0.f, 0.f, 0.f, 0.f};

    // stage(it): 9 groups of 16 rows x 64 B (rows tb..tb+143; consumed <= tb+129)
    auto stage = [&](int it) {
        short* dst = As[it & 1];
        int cib = it * 32;
        for (int j = wave; j < 9; j += 4)
            gl2lds16(A + (tb + j * 16 + srow) * DD + cib + scs, &dst[j * 512]);
    };

    stage(0);
    __syncthreads();

    for (int it = 0; it < 16; ++it) {
        if (it < 15) stage(it + 1);
        const short* Asb = As[it & 1];
        short8 bf[3][2];
#pragma unroll
        for (int k = 0; k < 3; ++k)
#pragma unroll
            for (int ni = 0; ni < 2; ++ni)
                bf[k][ni] = *(const short8*)(WF + ((size_t)((k * 16 + it) * 32 + co0b + ni) << 9));
#pragma unroll
        for (int k = 0; k < 3; ++k) {
            short8 af[8];
#pragma unroll
            for (int mi = 0; mi < 8; ++mi) {
                int arow = mi * 16 + l15 + k;
                af[mi] = *(const short8*)&Asb[arow * 32 + ((quad ^ ((arow >> 1) & 3)) << 3)];
            }
#pragma unroll
            for (int mi = 0; mi < 8; ++mi)
#pragma unroll
                for (int ni = 0; ni < 2; ++ni)
                    acc[mi][ni] = __builtin_amdgcn_mfma_f32_16x16x32_bf16(af[mi], bf[k][ni], acc[mi][ni], 0, 0, 0);
        }
        __syncthreads();
    }

    const float* bias = (proj == 0) ? b11 : ((proj == 1) ? b12 : b13);
#pragma unroll
    for (int ni = 0; ni < 2; ++ni) {
        int co = cb + wave * 32 + ni * 16 + l15;
        float bv = bias[co];
        int h = co >> 6, hd = co & 63;
        int bh = b * HH + h;
#pragma unroll
        for (int mi = 0; mi < 8; ++mi) {
            int mi4 = mi & 3;
            int tbase = tb + mi * 16 + quad * 4;
            unsigned short bb[4];
            ushort4 pk;
#pragma unroll
            for (int r = 0; r < 4; ++r) {
                float val = fmaxf(acc[mi][ni][r] + bv, 0.f);
                bb[r] = f2bf(val);
                ((unsigned short*)&pk)[r] = bb[r];
            }
            if (proj == 0) {
#pragma unroll
                for (int r = 0; r < 4; ++r)
                    q[((size_t)bh * TT + tbase + r) * HDIM + hd] = bb[r];
                *(ushort4*)&qt[((size_t)bh * HDIM + hd) * TT + tbase] = pk;
            } else if (proj == 1) {
                *(ushort4*)&kt[((size_t)bh * HDIM + hd) * TT + tbase] = pk;
                // K-frag layout: [bh][sblk][jr][kf][quad_a*16+l15a][8]
                int sblk = tbase >> 6;
                int jr = (quad & 1) + 2 * (mi4 >> 1);
                int l15a_base = 4 * (quad >> 1) + 8 * (mi4 & 1);  // + r
                int kf = hd >> 5, quad_a = (hd >> 3) & 3, elem = hd & 7;
                size_t base = ((((size_t)bh * 16 + sblk) * 4 + jr) * 2 + kf) * 512 +
                              quad_a * 128 + elem;
#pragma unroll
                for (int r = 0; r < 4; ++r)
                    kfrag[base + (l15a_base + r) * 8] = bb[r];
            } else {
#pragma unroll
                for (int r = 0; r < 4; ++r)
                    v[((size_t)bh * TT + tbase + r) * HDIM + hd] = bb[r];
                // Vt-frag layout: [bh][sblk][df][kf][quad_a*16+l15a][8]
                int sblk = tbase >> 6;
                int df = hd >> 4, l15a = hd & 15;
                int kf = mi4 >> 1;
                int quad_a = 2 * (mi4 & 1) + (quad >> 1);
                int elem = (quad & 1) * 4;
                size_t base = ((((size_t)bh * 16 + sblk) * 4 + df) * 2 + kf) * 512 +
                              (quad_a * 16 + l15a) * 8 + elem;
                *(ushort4*)&vtfrag[base] = pk;
            }
        }
    }
}

// ---------------- fused: time attention (x<16) + chan Gram partials (x>=16) ----------
// grid (20, B*H=64), block 256.
__global__ __launch_bounds__(256) void k_attn_gram(
    const unsigned short* __restrict__ q, const unsigned short* __restrict__ kfrag,
    const unsigned short* __restrict__ vtfrag, const unsigned short* __restrict__ qt,
    const unsigned short* __restrict__ kt, float* __restrict__ gbuf,
    unsigned short* __restrict__ vp) {
    int wave = threadIdx.x >> 6, lane = threadIdx.x & 63;
    int l15 = lane & 15, quad = lane >> 4;
    int bh = blockIdx.y;

    if (blockIdx.x < 16) {
        // ---- time attention: all-register flash, lane-linear frag loads ----
        int b = bh >> 3, h = bh & 7;
        int qr = blockIdx.x * 64 + wave * 16;
        const short* Q = (const short*)q + (size_t)bh * TT * HDIM;
        const short* KF = (const short*)kfrag + (size_t)bh * 16 * 8 * 512 + lane * 8;
        const short* VF = (const short*)vtfrag + (size_t)bh * 16 * 8 * 512 + lane * 8;

        short8 bq[2];
#pragma unroll
        for (int kf = 0; kf < 2; ++kf)
            bq[kf] = *(const short8*)(Q + (qr + l15) * HDIM + kf * 32 + quad * 8);

        floatx4 o[4];  // O^T accum: d = df*16 + quad*4 + r, q = l15
#pragma unroll
        for (int df = 0; df < 4; ++df) o[df] = (floatx4){0.f, 0.f, 0.f, 0.f};
        float lacc = 0.f;

        for (int sblk = 0; sblk < 16; ++sblk) {
            const short* kp = KF + sblk * 8 * 512;
            const short* vv = VF + sblk * 8 * 512;
            floatx4 c[4];
#pragma unroll
            for (int jr = 0; jr < 4; ++jr) c[jr] = (floatx4){0.f, 0.f, 0.f, 0.f};
#pragma unroll
            for (int jr = 0; jr < 4; ++jr) {
#pragma unroll
                for (int kf = 0; kf < 2; ++kf) {
                    short8 ak = *(const short8*)(kp + (jr * 2 + kf) * 512);
                    c[jr] = __builtin_amdgcn_mfma_f32_16x16x32_bf16(ak, bq[kf], c[jr], 0, 0, 0);
                }
            }
            short8 pb[2];
#pragma unroll
            for (int kf = 0; kf < 2; ++kf) {
                union { short8 s; unsigned u[4]; } pk;
#pragma unroll
                for (int half = 0; half < 2; ++half) {
                    floatx4 cc = c[2 * kf + half];
                    float p0 = __expf(cc[0] * 0.125f);
                    float p1 = __expf(cc[1] * 0.125f);
                    float p2 = __expf(cc[2] * 0.125f);
                    float p3 = __expf(cc[3] * 0.125f);
                    lacc += (p0 + p1) + (p2 + p3);
                    pk.u[half * 2] =
                        __builtin_amdgcn_perm(__float_as_uint(p1), __float_as_uint(p0), 0x07060302u);
                    pk.u[half * 2 + 1] =
                        __builtin_amdgcn_perm(__float_as_uint(p3), __float_as_uint(p2), 0x07060302u);
                }
                pb[kf] = pk.s;
            }
#pragma unroll
            for (int df = 0; df < 4; ++df) {
#pragma unroll
                for (int kf = 0; kf < 2; ++kf) {
                    short8 av = *(const short8*)(vv + (df * 2 + kf) * 512);
                    o[df] = __builtin_amdgcn_mfma_f32_16x16x32_bf16(av, pb[kf], o[df], 0, 0, 0);
                }
            }
        }

        lacc += __shfl_xor(lacc, 16);
        lacc += __shfl_xor(lacc, 32);
        float linv = 1.f / lacc;

        unsigned short* vrow = vp + (size_t)(b * TP + 1 + qr + l15) * (2 * DD) + h * 64;
#pragma unroll
        for (int df = 0; df < 4; ++df) {
            ushort4 pk;
#pragma unroll
            for (int r = 0; r < 4; ++r) ((unsigned short*)&pk)[r] = f2bf(o[df][r] * linv);
            *(ushort4*)&vrow[df * 16 + quad * 4] = pk;
        }
    } else {
        // ---- chan Gram partials (4-way T split) ----
        int tc = blockIdx.x - 16;
        const short* Qt = (const short*)qt + (size_t)bh * HDIM * TT;
        const short* Kt = (const short*)kt + (size_t)bh * HDIM * TT;

        floatx4 g[4];
#pragma unroll
        for (int nt = 0; nt < 4; ++nt) g[nt] = (floatx4){0.f, 0.f, 0.f, 0.f};

        int t0b = tc * 256;
        for (int t0 = 0; t0 < 256; t0 += 32) {
            short8 aq = *(const short8*)(Qt + (wave * 16 + l15) * TT + t0b + t0 + quad * 8);
#pragma unroll
            for (int nt = 0; nt < 4; ++nt) {
                short8 bk = *(const short8*)(Kt + (nt * 16 + l15) * TT + t0b + t0 + quad * 8);
                g[nt] = __builtin_amdgcn_mfma_f32_16x16x32_bf16(aq, bk, g[nt], 0, 0, 0);
            }
        }
        float* gb = gbuf + bh * HDIM * HDIM;
#pragma unroll
        for (int nt = 0; nt < 4; ++nt) {
#pragma unroll
            for (int r = 0; r < 4; ++r) {
                int row = wave * 16 + quad * 4 + r;
                atomicAdd(&gb[row * HDIM + nt * 16 + l15], g[nt][r]);
            }
        }
    }
}

// ---------------- channel attention: softmax + A.V (4-way T split) ----------------
__global__ __launch_bounds__(256) void k_chan_av(
    const float* __restrict__ gbuf, const unsigned short* __restrict__ v,
    unsigned short* __restrict__ vp) {
    __shared__ short lds_a[64 * 64];
    int wave = threadIdx.x >> 6, lane = threadIdx.x & 63;
    int l15 = lane & 15, quad = lane >> 4;
    int tc = blockIdx.x, bh = blockIdx.y;
    int b = bh >> 3, h = bh & 7;
    const float sc = 0.03125f;  // 1/sqrt(1024)

    if (threadIdx.x < 64) {
        const float* gb = gbuf + bh * HDIM * HDIM + threadIdx.x * HDIM;
        float mx = -3.0e38f;
        for (int j = 0; j < 64; ++j) mx = fmaxf(mx, gb[j] * sc);
        float sum = 0.f;
        for (int j = 0; j < 64; ++j) sum += __expf(gb[j] * sc - mx);
        float inv = 1.f / sum;
        for (int j = 0; j < 64; ++j)
            lds_a[threadIdx.x * 64 + j] = (short)f2bf(__expf(gb[j] * sc - mx) * inv);
    }
    __syncthreads();

    const short* V = (const short*)v + (size_t)bh * TT * HDIM;
    short8 pa[2];
#pragma unroll
    for (int kf = 0; kf < 2; ++kf)
        pa[kf] = *(const short8*)&lds_a[(wave * 16 + l15) * 64 + kf * 32 + quad * 8];

    for (int tt = 0; tt < 16; ++tt) {
        int ttile = tc * 16 + tt;
        floatx4 c = (floatx4){0.f, 0.f, 0.f, 0.f};
#pragma unroll
        for (int kf = 0; kf < 2; ++kf) {
            short8 bv = *(const short8*)(V + (ttile * 16 + l15) * HDIM + kf * 32 + quad * 8);
            c = __builtin_amdgcn_mfma_f32_16x16x32_bf16(pa[kf], bv, c, 0, 0, 0);
        }
        int t = ttile * 16 + l15;
#pragma unroll
        for (int r = 0; r < 4; ++r) {
            int crow = wave * 16 + quad * 4 + r;
            int tout = crow * 16 + (t >> 6);
            int col = 512 + ((t & 63) << 3) + h;
            vp[(b * TP + 1 + tout) * (2 * DD) + col] = f2bf(c[r]);
        }
    }
}

// ---------------- output conv: R10 shape (128x64 tile, BK=64, 2x2 split) -------------
// grid (T/128=8, 512/64=8, B=8) = 512 blocks; part of the proven 240 us config.
__global__ __launch_bounds__(256) void k_out_conv(
    const unsigned short* __restrict__ vp, const unsigned short* __restrict__ w2k,
    const float* __restrict__ b2, float* __restrict__ out) {
    __shared__ short As[2][144 * 64];
    int wave = threadIdx.x >> 6, lane = threadIdx.x & 63;
    int l15 = lane & 15, quad = lane >> 4;
    int wm = wave >> 1, wn = wave & 1;
    int tb = blockIdx.x * 128;
    int cb = blockIdx.y * 64;
    int b = blockIdx.z;
    const short* A = (const short*)vp + b * TP * DD2;
    const short* WF = (const short*)w2k + lane * 8;
    int srow8 = lane >> 3;
    int scl = ((lane & 7) ^ srow8) * 8;
    int co0b = (cb >> 4) + wn * 2;

    floatx4 acc[4][2];
#pragma unroll
    for (int mi = 0; mi < 4; ++mi)
#pragma unroll
        for (int ni = 0; ni < 2; ++ni) acc[mi][ni] = (floatx4){0.f, 0.f, 0.f, 0.f};

    auto stage = [&](int it) {
        short* dst = As[it & 1];
        int cib = it * 64;
        for (int g = wave; g < 18; g += 4) {
            int j = g >> 1, hf = g & 1;
            int row = hf * 8 + srow8;
            gl2lds16(A + (tb + j * 16 + row) * DD2 + cib + scl, &dst[j * 1024 + hf * 512]);
        }
    };

    stage(0);
    __syncthreads();

    for (int it = 0; it < 16; ++it) {
        if (it < 15) stage(it + 1);
        const short* Asb = As[it & 1];
#pragma unroll
        for (int k = 0; k < 3; ++k) {
            short8 bf[2][2];
#pragma unroll
            for (int kfh = 0; kfh < 2; ++kfh)
#pragma unroll
                for (int ni = 0; ni < 2; ++ni)
                    bf[kfh][ni] = *(const short8*)(WF +
                        ((size_t)((k * 32 + it * 2 + kfh) * 32 + co0b + ni) << 9));
#pragma unroll
            for (int kfh = 0; kfh < 2; ++kfh) {
                short8 af[4];
#pragma unroll
                for (int mi = 0; mi < 4; ++mi) {
                    int arow = wm * 64 + mi * 16 + l15 + k;
                    int cl = kfh * 4 + quad;
                    af[mi] = *(const short8*)&Asb[arow * 64 + ((cl ^ (arow & 7)) << 3)];
                }
#pragma unroll
                for (int mi = 0; mi < 4; ++mi)
#pragma unroll
                    for (int ni = 0; ni < 2; ++ni)
                        acc[mi][ni] = __builtin_amdgcn_mfma_f32_16x16x32_bf16(af[mi], bf[kfh][ni], acc[mi][ni], 0, 0, 0);
            }
        }
        __syncthreads();
    }

#pragma unroll
    for (int ni = 0; ni < 2; ++ni) {
        int co = cb + wn * 32 + ni * 16 + l15;
        float bv = b2[co];
#pragma unroll
        for (int mi = 0; mi < 4; ++mi) {
#pragma unroll
            for (int r = 0; r < 4; ++r) {
                int t = tb + wm * 64 + mi * 16 + quad * 4 + r;
                out[((size_t)b * TT + t) * DD + co] = fmaxf(acc[mi][ni][r] + bv, 0.f);
            }
        }
    }
}

extern "C" void kernel_launch(void* const* d_in, const int* in_sizes, int n_in,
                              void* d_out, int out_size, void* d_ws, size_t ws_size,
                              hipStream_t stream) {
    const float* x = (const float*)d_in[0];
    const float* w11 = (const float*)d_in[1];
    const float* b11 = (const float*)d_in[2];
    const float* w12 = (const float*)d_in[3];
    const float* b12 = (const float*)d_in[4];
    const float* w13 = (const float*)d_in[5];
    const float* b13 = (const float*)d_in[6];
    const float* w2 = (const float*)d_in[7];
    const float* b2 = (const float*)d_in[8];
    float* out = (float*)d_out;

    char* ws = (char*)d_ws;
    size_t off = 0;
    auto alloc = [&](size_t bytes) {
        void* p = ws + off;
        off += (bytes + 255) & ~(size_t)255;
        return p;
    };
    unsigned short* xp = (unsigned short*)alloc((size_t)BB * TP * DD * 2);
    unsigned short* wqkv = (unsigned short*)alloc((size_t)9 * DD * DD * 2);
    unsigned short* w2k = (unsigned short*)alloc((size_t)3 * DD * DD2 * 2);
    unsigned short* q = (unsigned short*)alloc((size_t)BB * HH * TT * HDIM * 2);
    unsigned short* qt = (unsigned short*)alloc((size_t)BB * HH * TT * HDIM * 2);
    unsigned short* kfrag = (unsigned short*)alloc((size_t)BB * HH * TT * HDIM * 2);
    unsigned short* kt = (unsigned short*)alloc((size_t)BB * HH * TT * HDIM * 2);
    unsigned short* v = (unsigned short*)alloc((size_t)BB * HH * TT * HDIM * 2);
    unsigned short* vtfrag = (unsigned short*)alloc((size_t)BB * HH * TT * HDIM * 2);
    float* gbuf = (float*)alloc((size_t)64 * HDIM * HDIM * 4);
    unsigned short* vp = (unsigned short*)alloc((size_t)BB * TP * 2 * DD * 2);
    (void)alloc(65536);  // guard: halo staging reads up to 14 rows past buffer ends

    k_prep<<<NXBLK + NW1BLK + NW2BLK + NZBLK, 256, 0, stream>>>(x, w11, w12, w13, w2,
                                                                xp, wqkv, w2k, vp, gbuf);
    k_qkv_conv<<<dim3(TT / 128, DD / 128, BB * 3), 256, 0, stream>>>(xp, wqkv, b11, b12, b13,
                                                                     q, qt, kfrag, kt, v, vtfrag);
    k_attn_gram<<<dim3(20, BB * HH), 256, 0, stream>>>(q, kfrag, vtfrag, qt, kt, gbuf, vp);
    k_chan_av<<<dim3(4, BB * HH), 256, 0, stream>>>(gbuf, v, vp);
    k_out_conv<<<dim3(TT / 128, DD / 64, BB), 256, 0, stream>>>(vp, w2k, b2, out);
}

// Round 14
// 238.744 us; speedup vs baseline: 1.2116x; 1.0168x over previous
//
#include <hip/hip_runtime.h>

#define BB 8
#define TT 1024
#define DD 512
#define DD2 1024
#define HH 8
#define HDIM 64
#define TP (TT + 2)

typedef short short8 __attribute__((ext_vector_type(8)));
typedef float floatx4 __attribute__((ext_vector_type(4)));

typedef const __attribute__((address_space(1))) unsigned int* gas_ptr;
typedef __attribute__((address_space(3))) unsigned int* las_ptr;

__device__ __forceinline__ unsigned short f2bf(float f) {
    union { float f; unsigned u; } v; v.f = f;
    unsigned r = v.u + 0x7fffu + ((v.u >> 16) & 1u);
    return (unsigned short)(r >> 16);
}

// async global->LDS, 16B per lane, LDS dst = wave-uniform base + lane*16
__device__ __forceinline__ void gl2lds16(const void* g, void* l) {
    __builtin_amdgcn_global_load_lds((gas_ptr)g, (las_ptr)l, 16, 0, 0);
}

// ---------------- fused prep kernel ----------------
#define NX4BLK 4104   // x convert, float4-vectorized: 8*1026*512/4/256
#define NW1BLK 9216
#define NW2BLK 6144
#define NZBLK 1024
__global__ void k_prep(const float* __restrict__ x, const float* __restrict__ w0,
                       const float* __restrict__ w1, const float* __restrict__ w2,
                       const float* __restrict__ wo,
                       unsigned short* __restrict__ xp, unsigned short* __restrict__ wqkv,
                       unsigned short* __restrict__ w2k, unsigned short* __restrict__ vp,
                       float* __restrict__ gbuf) {
    int blk = blockIdx.x;
    if (blk < NX4BLK) {
        int idx = blk * 256 + threadIdx.x;
        int c4 = idx % (DD / 4);
        int rt = idx / (DD / 4);
        int row = rt % TP;
        int b = rt / TP;
        ushort4 o = {0, 0, 0, 0};
        if (row >= 1 && row <= TT) {
            float4 vv = *(const float4*)&x[((size_t)(b * TT + row - 1)) * DD + c4 * 4];
            o.x = f2bf(vv.x); o.y = f2bf(vv.y); o.z = f2bf(vv.z); o.w = f2bf(vv.w);
        }
        *(ushort4*)&xp[(size_t)idx * 4] = o;
        return;
    }
    blk -= NX4BLK;
    if (blk < NW1BLK) {
        // W(qkv) B-frag-major: [proj][k][ci0(16)][co0(32)][lane(64)][e(8)]
        int idx = blk * 256 + threadIdx.x;
        int e = idx & 7;
        int lane = (idx >> 3) & 63;
        int co0 = (idx >> 9) & 31;
        int ci0 = (idx >> 14) & 15;
        int rest = idx >> 18;
        int k = rest % 3, p = rest / 3;
        int co = co0 * 16 + (lane & 15);
        int ci = ci0 * 32 + (lane >> 4) * 8 + e;
        const float* w = (p == 0) ? w0 : ((p == 1) ? w1 : w2);
        wqkv[idx] = f2bf(w[(co * DD + ci) * 3 + k]);
        return;
    }
    blk -= NW1BLK;
    if (blk < NW2BLK) {
        // W2 B-frag-major: [k][ci0(32)][co0(32)][lane(64)][e(8)]
        int idx = blk * 256 + threadIdx.x;
        int e = idx & 7;
        int lane = (idx >> 3) & 63;
        int co0 = (idx >> 9) & 31;
        int ci0 = (idx >> 14) & 31;
        int k = idx >> 19;
        int co = co0 * 16 + (lane & 15);
        int ci = ci0 * 32 + (lane >> 4) * 8 + e;
        w2k[idx] = f2bf(wo[(co * DD2 + ci) * 3 + k]);
        return;
    }
    blk -= NW2BLK;
    {
        int idx = blk * 256 + threadIdx.x;
        if (idx < BB * 2 * 2 * DD) {
            int c = idx % (2 * DD);
            int t1 = idx / (2 * DD);
            int row = (t1 & 1) ? (TT + 1) : 0;
            int b = t1 >> 1;
            vp[(b * TP + row) * (2 * DD) + c] = 0;
        }
        if (idx < 64 * HDIM * HDIM) gbuf[idx] = 0.f;
    }
}

// ---------------- QKV conv: R10-verified 64x128 tile, BK=32 dbuf, pure-N split --------
// grid (T/64=16, 512/128=4, B*3=24) = 1536 blocks (54 us, MfmaUtil 28.6%, 0 conflicts).
__global__ __launch_bounds__(256) void k_qkv_conv(
    const unsigned short* __restrict__ xp, const unsigned short* __restrict__ wfrag,
    const float* __restrict__ b11, const float* __restrict__ b12, const float* __restrict__ b13,
    unsigned short* __restrict__ q, unsigned short* __restrict__ qt,
    unsigned short* __restrict__ kfrag, unsigned short* __restrict__ kt,
    unsigned short* __restrict__ v, unsigned short* __restrict__ vtfrag) {
    __shared__ short As[2][80 * 32];
    int wave = threadIdx.x >> 6, lane = threadIdx.x & 63;
    int l15 = lane & 15, quad = lane >> 4;
    int tb = blockIdx.x * 64;
    int cb = blockIdx.y * 128;
    int proj = blockIdx.z % 3, b = blockIdx.z / 3;
    const short* A = (const short*)xp + b * TP * DD;
    const short* WF = (const short*)wfrag + (size_t)proj * 786432 + lane * 8;
    int srow = lane >> 2;
    int scs = (((lane & 3) ^ ((lane >> 3) & 3)) << 3);
    int co0b = (cb >> 4) + wave * 2;

    floatx4 acc[4][2];
#pragma unroll
    for (int mi = 0; mi < 4; ++mi)
#pragma unroll
        for (int ni = 0; ni < 2; ++ni) acc[mi][ni] = (floatx4){0.f, 0.f, 0.f, 0.f};

    auto stage = [&](int it) {
        short* dst = As[it & 1];
        int cib = it * 32;
        for (int j = wave; j < 5; j += 4)
            gl2lds16(A + (tb + j * 16 + srow) * DD + cib + scs, &dst[j * 512]);
    };

    stage(0);
    __syncthreads();

    for (int it = 0; it < 16; ++it) {
        if (it < 15) stage(it + 1);
        const short* Asb = As[it & 1];
        short8 bf[3][2];
#pragma unroll
        for (int k = 0; k < 3; ++k)
#pragma unroll
            for (int ni = 0; ni < 2; ++ni)
                bf[k][ni] = *(const short8*)(WF + ((size_t)((k * 16 + it) * 32 + co0b + ni) << 9));
#pragma unroll
        for (int k = 0; k < 3; ++k) {
            short8 af[4];
#pragma unroll
            for (int mi = 0; mi < 4; ++mi) {
                int arow = mi * 16 + l15 + k;
                af[mi] = *(const short8*)&Asb[arow * 32 + ((quad ^ ((arow >> 1) & 3)) << 3)];
            }
#pragma unroll
            for (int mi = 0; mi < 4; ++mi)
#pragma unroll
                for (int ni = 0; ni < 2; ++ni)
                    acc[mi][ni] = __builtin_amdgcn_mfma_f32_16x16x32_bf16(af[mi], bf[k][ni], acc[mi][ni], 0, 0, 0);
        }
        __syncthreads();
    }

    const float* bias = (proj == 0) ? b11 : ((proj == 1) ? b12 : b13);
#pragma unroll
    for (int ni = 0; ni < 2; ++ni) {
        int co = cb + wave * 32 + ni * 16 + l15;
        float bv = bias[co];
        int h = co >> 6, hd = co & 63;
        int bh = b * HH + h;
#pragma unroll
        for (int mi = 0; mi < 4; ++mi) {
            int tbase = tb + mi * 16 + quad * 4;
            unsigned short bb[4];
            ushort4 pk;
#pragma unroll
            for (int r = 0; r < 4; ++r) {
                float val = fmaxf(acc[mi][ni][r] + bv, 0.f);
                bb[r] = f2bf(val);
                ((unsigned short*)&pk)[r] = bb[r];
            }
            if (proj == 0) {
#pragma unroll
                for (int r = 0; r < 4; ++r)
                    q[((size_t)bh * TT + tbase + r) * HDIM + hd] = bb[r];
                *(ushort4*)&qt[((size_t)bh * HDIM + hd) * TT + tbase] = pk;
            } else if (proj == 1) {
                *(ushort4*)&kt[((size_t)bh * HDIM + hd) * TT + tbase] = pk;
                // K-frag layout: [bh][sblk][jr][kf][quad_a*16+l15a][8]
                int sblk = tbase >> 6;
                int jr = (quad & 1) + 2 * (mi >> 1);
                int l15a_base = 4 * (quad >> 1) + 8 * (mi & 1);  // + r
                int kf = hd >> 5, quad_a = (hd >> 3) & 3, elem = hd & 7;
                size_t base = ((((size_t)bh * 16 + sblk) * 4 + jr) * 2 + kf) * 512 +
                              quad_a * 128 + elem;
#pragma unroll
                for (int r = 0; r < 4; ++r)
                    kfrag[base + (l15a_base + r) * 8] = bb[r];
            } else {
#pragma unroll
                for (int r = 0; r < 4; ++r)
                    v[((size_t)bh * TT + tbase + r) * HDIM + hd] = bb[r];
                // Vt-frag layout: [bh][sblk][df][kf][quad_a*16+l15a][8]
                int sblk = tbase >> 6;
                int df = hd >> 4, l15a = hd & 15;
                int kf = mi >> 1;
                int quad_a = 2 * (mi & 1) + (quad >> 1);
                int elem = (quad & 1) * 4;
                size_t base = ((((size_t)bh * 16 + sblk) * 4 + df) * 2 + kf) * 512 +
                              (quad_a * 16 + l15a) * 8 + elem;
                *(ushort4*)&vtfrag[base] = pk;
            }
        }
    }
}

// ---------------- fused: time attention (x<16) + chan Gram partials (x>=16) ----------
// grid (20, B*H=64), block 256.
__global__ __launch_bounds__(256) void k_attn_gram(
    const unsigned short* __restrict__ q, const unsigned short* __restrict__ kfrag,
    const unsigned short* __restrict__ vtfrag, const unsigned short* __restrict__ qt,
    const unsigned short* __restrict__ kt, float* __restrict__ gbuf,
    unsigned short* __restrict__ vp) {
    int wave = threadIdx.x >> 6, lane = threadIdx.x & 63;
    int l15 = lane & 15, quad = lane >> 4;
    int bh = blockIdx.y;

    if (blockIdx.x < 16) {
        // ---- time attention: all-register flash, lane-linear frag loads ----
        int b = bh >> 3, h = bh & 7;
        int qr = blockIdx.x * 64 + wave * 16;
        const short* Q = (const short*)q + (size_t)bh * TT * HDIM;
        const short* KF = (const short*)kfrag + (size_t)bh * 16 * 8 * 512 + lane * 8;
        const short* VF = (const short*)vtfrag + (size_t)bh * 16 * 8 * 512 + lane * 8;

        short8 bq[2];
#pragma unroll
        for (int kf = 0; kf < 2; ++kf)
            bq[kf] = *(const short8*)(Q + (qr + l15) * HDIM + kf * 32 + quad * 8);

        floatx4 o[4];  // O^T accum: d = df*16 + quad*4 + r, q = l15
#pragma unroll
        for (int df = 0; df < 4; ++df) o[df] = (floatx4){0.f, 0.f, 0.f, 0.f};
        float lacc = 0.f;

        for (int sblk = 0; sblk < 16; ++sblk) {
            const short* kp = KF + sblk * 8 * 512;
            const short* vv = VF + sblk * 8 * 512;
            floatx4 c[4];
#pragma unroll
            for (int jr = 0; jr < 4; ++jr) c[jr] = (floatx4){0.f, 0.f, 0.f, 0.f};
#pragma unroll
            for (int jr = 0; jr < 4; ++jr) {
#pragma unroll
                for (int kf = 0; kf < 2; ++kf) {
                    short8 ak = *(const short8*)(kp + (jr * 2 + kf) * 512);
                    c[jr] = __builtin_amdgcn_mfma_f32_16x16x32_bf16(ak, bq[kf], c[jr], 0, 0, 0);
                }
            }
            short8 pb[2];
#pragma unroll
            for (int kf = 0; kf < 2; ++kf) {
                union { short8 s; unsigned u[4]; } pk;
#pragma unroll
                for (int half = 0; half < 2; ++half) {
                    floatx4 cc = c[2 * kf + half];
                    float p0 = __expf(cc[0] * 0.125f);
                    float p1 = __expf(cc[1] * 0.125f);
                    float p2 = __expf(cc[2] * 0.125f);
                    float p3 = __expf(cc[3] * 0.125f);
                    lacc += (p0 + p1) + (p2 + p3);
                    pk.u[half * 2] =
                        __builtin_amdgcn_perm(__float_as_uint(p1), __float_as_uint(p0), 0x07060302u);
                    pk.u[half * 2 + 1] =
                        __builtin_amdgcn_perm(__float_as_uint(p3), __float_as_uint(p2), 0x07060302u);
                }
                pb[kf] = pk.s;
            }
#pragma unroll
            for (int df = 0; df < 4; ++df) {
#pragma unroll
                for (int kf = 0; kf < 2; ++kf) {
                    short8 av = *(const short8*)(vv + (df * 2 + kf) * 512);
                    o[df] = __builtin_amdgcn_mfma_f32_16x16x32_bf16(av, pb[kf], o[df], 0, 0, 0);
                }
            }
        }

        lacc += __shfl_xor(lacc, 16);
        lacc += __shfl_xor(lacc, 32);
        float linv = 1.f / lacc;

        unsigned short* vrow = vp + (size_t)(b * TP + 1 + qr + l15) * (2 * DD) + h * 64;
#pragma unroll
        for (int df = 0; df < 4; ++df) {
            ushort4 pk;
#pragma unroll
            for (int r = 0; r < 4; ++r) ((unsigned short*)&pk)[r] = f2bf(o[df][r] * linv);
            *(ushort4*)&vrow[df * 16 + quad * 4] = pk;
        }
    } else {
        // ---- chan Gram partials (4-way T split) ----
        int tc = blockIdx.x - 16;
        const short* Qt = (const short*)qt + (size_t)bh * HDIM * TT;
        const short* Kt = (const short*)kt + (size_t)bh * HDIM * TT;

        floatx4 g[4];
#pragma unroll
        for (int nt = 0; nt < 4; ++nt) g[nt] = (floatx4){0.f, 0.f, 0.f, 0.f};

        int t0b = tc * 256;
        for (int t0 = 0; t0 < 256; t0 += 32) {
            short8 aq = *(const short8*)(Qt + (wave * 16 + l15) * TT + t0b + t0 + quad * 8);
#pragma unroll
            for (int nt = 0; nt < 4; ++nt) {
                short8 bk = *(const short8*)(Kt + (nt * 16 + l15) * TT + t0b + t0 + quad * 8);
                g[nt] = __builtin_amdgcn_mfma_f32_16x16x32_bf16(aq, bk, g[nt], 0, 0, 0);
            }
        }
        float* gb = gbuf + bh * HDIM * HDIM;
#pragma unroll
        for (int nt = 0; nt < 4; ++nt) {
#pragma unroll
            for (int r = 0; r < 4; ++r) {
                int row = wave * 16 + quad * 4 + r;
                atomicAdd(&gb[row * HDIM + nt * 16 + l15], g[nt][r]);
            }
        }
    }
}

// ---------------- channel attention: softmax + A.V (4-way T split) ----------------
__global__ __launch_bounds__(256) void k_chan_av(
    const float* __restrict__ gbuf, const unsigned short* __restrict__ v,
    unsigned short* __restrict__ vp) {
    __shared__ short lds_a[64 * 64];
    int wave = threadIdx.x >> 6, lane = threadIdx.x & 63;
    int l15 = lane & 15, quad = lane >> 4;
    int tc = blockIdx.x, bh = blockIdx.y;
    int b = bh >> 3, h = bh & 7;
    const float sc = 0.03125f;  // 1/sqrt(1024)

    if (threadIdx.x < 64) {
        const float* gb = gbuf + bh * HDIM * HDIM + threadIdx.x * HDIM;
        float mx = -3.0e38f;
        for (int j = 0; j < 64; ++j) mx = fmaxf(mx, gb[j] * sc);
        float sum = 0.f;
        for (int j = 0; j < 64; ++j) sum += __expf(gb[j] * sc - mx);
        float inv = 1.f / sum;
        for (int j = 0; j < 64; ++j)
            lds_a[threadIdx.x * 64 + j] = (short)f2bf(__expf(gb[j] * sc - mx) * inv);
    }
    __syncthreads();

    const short* V = (const short*)v + (size_t)bh * TT * HDIM;
    short8 pa[2];
#pragma unroll
    for (int kf = 0; kf < 2; ++kf)
        pa[kf] = *(const short8*)&lds_a[(wave * 16 + l15) * 64 + kf * 32 + quad * 8];

    for (int tt = 0; tt < 16; ++tt) {
        int ttile = tc * 16 + tt;
        floatx4 c = (floatx4){0.f, 0.f, 0.f, 0.f};
#pragma unroll
        for (int kf = 0; kf < 2; ++kf) {
            short8 bv = *(const short8*)(V + (ttile * 16 + l15) * HDIM + kf * 32 + quad * 8);
            c = __builtin_amdgcn_mfma_f32_16x16x32_bf16(pa[kf], bv, c, 0, 0, 0);
        }
        int t = ttile * 16 + l15;
#pragma unroll
        for (int r = 0; r < 4; ++r) {
            int crow = wave * 16 + quad * 4 + r;
            int tout = crow * 16 + (t >> 6);
            int col = 512 + ((t & 63) << 3) + h;
            vp[(b * TP + 1 + tout) * (2 * DD) + col] = f2bf(c[r]);
        }
    }
}

// ---------------- output conv: R10 shape (128x64 tile, BK=64, 2x2 split) -------------
// grid (T/128=8, 512/64=8, B=8) = 512 blocks; part of the proven 240 us config.
__global__ __launch_bounds__(256) void k_out_conv(
    const unsigned short* __restrict__ vp, const unsigned short* __restrict__ w2k,
    const float* __restrict__ b2, float* __restrict__ out) {
    __shared__ short As[2][144 * 64];
    int wave = threadIdx.x >> 6, lane = threadIdx.x & 63;
    int l15 = lane & 15, quad = lane >> 4;
    int wm = wave >> 1, wn = wave & 1;
    int tb = blockIdx.x * 128;
    int cb = blockIdx.y * 64;
    int b = blockIdx.z;
    const short* A = (const short*)vp + b * TP * DD2;
    const short* WF = (const short*)w2k + lane * 8;
    int srow8 = lane >> 3;
    int scl = ((lane & 7) ^ srow8) * 8;
    int co0b = (cb >> 4) + wn * 2;

    floatx4 acc[4][2];
#pragma unroll
    for (int mi = 0; mi < 4; ++mi)
#pragma unroll
        for (int ni = 0; ni < 2; ++ni) acc[mi][ni] = (floatx4){0.f, 0.f, 0.f, 0.f};

    auto stage = [&](int it) {
        short* dst = As[it & 1];
        int cib = it * 64;
        for (int g = wave; g < 18; g += 4) {
            int j = g >> 1, hf = g & 1;
            int row = hf * 8 + srow8;
            gl2lds16(A + (tb + j * 16 + row) * DD2 + cib + scl, &dst[j * 1024 + hf * 512]);
        }
    };

    stage(0);
    __syncthreads();

    for (int it = 0; it < 16; ++it) {
        if (it < 15) stage(it + 1);
        const short* Asb = As[it & 1];
#pragma unroll
        for (int k = 0; k < 3; ++k) {
            short8 bf[2][2];
#pragma unroll
            for (int kfh = 0; kfh < 2; ++kfh)
#pragma unroll
                for (int ni = 0; ni < 2; ++ni)
                    bf[kfh][ni] = *(const short8*)(WF +
                        ((size_t)((k * 32 + it * 2 + kfh) * 32 + co0b + ni) << 9));
#pragma unroll
            for (int kfh = 0; kfh < 2; ++kfh) {
                short8 af[4];
#pragma unroll
                for (int mi = 0; mi < 4; ++mi) {
                    int arow = wm * 64 + mi * 16 + l15 + k;
                    int cl = kfh * 4 + quad;
                    af[mi] = *(const short8*)&Asb[arow * 64 + ((cl ^ (arow & 7)) << 3)];
                }
#pragma unroll
                for (int mi = 0; mi < 4; ++mi)
#pragma unroll
                    for (int ni = 0; ni < 2; ++ni)
                        acc[mi][ni] = __builtin_amdgcn_mfma_f32_16x16x32_bf16(af[mi], bf[kfh][ni], acc[mi][ni], 0, 0, 0);
            }
        }
        __syncthreads();
    }

#pragma unroll
    for (int ni = 0; ni < 2; ++ni) {
        int co = cb + wn * 32 + ni * 16 + l15;
        float bv = b2[co];
#pragma unroll
        for (int mi = 0; mi < 4; ++mi) {
#pragma unroll
            for (int r = 0; r < 4; ++r) {
                int t = tb + wm * 64 + mi * 16 + quad * 4 + r;
                out[((size_t)b * TT + t) * DD + co] = fmaxf(acc[mi][ni][r] + bv, 0.f);
            }
        }
    }
}

extern "C" void kernel_launch(void* const* d_in, const int* in_sizes, int n_in,
                              void* d_out, int out_size, void* d_ws, size_t ws_size,
                              hipStream_t stream) {
    const float* x = (const float*)d_in[0];
    const float* w11 = (const float*)d_in[1];
    const float* b11 = (const float*)d_in[2];
    const float* w12 = (const float*)d_in[3];
    const float* b12 = (const float*)d_in[4];
    const float* w13 = (const float*)d_in[5];
    const float* b13 = (const float*)d_in[6];
    const float* w2 = (const float*)d_in[7];
    const float* b2 = (const float*)d_in[8];
    float* out = (float*)d_out;

    char* ws = (char*)d_ws;
    size_t off = 0;
    auto alloc = [&](size_t bytes) {
        void* p = ws + off;
        off += (bytes + 255) & ~(size_t)255;
        return p;
    };
    unsigned short* xp = (unsigned short*)alloc((size_t)BB * TP * DD * 2);
    unsigned short* wqkv = (unsigned short*)alloc((size_t)9 * DD * DD * 2);
    unsigned short* w2k = (unsigned short*)alloc((size_t)3 * DD * DD2 * 2);
    unsigned short* q = (unsigned short*)alloc((size_t)BB * HH * TT * HDIM * 2);
    unsigned short* qt = (unsigned short*)alloc((size_t)BB * HH * TT * HDIM * 2);
    unsigned short* kfrag = (unsigned short*)alloc((size_t)BB * HH * TT * HDIM * 2);
    unsigned short* kt = (unsigned short*)alloc((size_t)BB * HH * TT * HDIM * 2);
    unsigned short* v = (unsigned short*)alloc((size_t)BB * HH * TT * HDIM * 2);
    unsigned short* vtfrag = (unsigned short*)alloc((size_t)BB * HH * TT * HDIM * 2);
    float* gbuf = (float*)alloc((size_t)64 * HDIM * HDIM * 4);
    unsigned short* vp = (unsigned short*)alloc((size_t)BB * TP * 2 * DD * 2);
    (void)alloc(65536);  // guard: halo staging reads up to 14 rows past buffer ends

    k_prep<<<NX4BLK + NW1BLK + NW2BLK + NZBLK, 256, 0, stream>>>(x, w11, w12, w13, w2,
                                                                 xp, wqkv, w2k, vp, gbuf);
    k_qkv_conv<<<dim3(TT / 64, DD / 128, BB * 3), 256, 0, stream>>>(xp, wqkv, b11, b12, b13,
                                                                    q, qt, kfrag, kt, v, vtfrag);
    k_attn_gram<<<dim3(20, BB * HH), 256, 0, stream>>>(q, kfrag, vtfrag, qt, kt, gbuf, vp);
    k_chan_av<<<dim3(4, BB * HH), 256, 0, stream>>>(gbuf, v, vp);
    k_out_conv<<<dim3(TT / 128, DD / 64, BB), 256, 0, stream>>>(vp, w2k, b2, out);
}